// Round 2
// baseline (765.406 us; speedup 1.0000x reference)
//
#include <hip/hip_runtime.h>

// VariableSelection (TFT-style) on gfx950. ALL I/O f32; bf16 MFMA internally.
// B=128 S=64 F=32 D=128 U=128 DS=128 DIN=262272, KMAIN=S*F*D=262144
// R5: k2 redesigned BARRIER-FREE: weights read directly from global (L2-hot,
//     pre-transposed bf16 [n][k]); xA/hA rows are per-wave private; LDS 34.8KB
//     -> 4 blocks/CU = 16 waves/CU; grid 1024 = bb(128) x fg(8, fast) so each
//     XCD keeps one fg's 512KB weight set hot in its private L2.
//     k1 unchanged (depth-2 reg prefetch + counted lgkm-only barrier).

typedef unsigned short u16;
typedef __attribute__((ext_vector_type(4))) u16 u16x4;
typedef __attribute__((ext_vector_type(8))) u16 u16x8;
typedef __attribute__((ext_vector_type(8))) __bf16 bf16x8;
typedef __attribute__((ext_vector_type(4))) float f32x4;

__device__ __forceinline__ u16 f2bf(float f) {
  unsigned int x = __float_as_uint(f);
  return (u16)((x + 0x7fffu + ((x >> 16) & 1u)) >> 16);  // RNE
}
__device__ __forceinline__ float eluf(float x) { return x > 0.f ? x : __expf(x) - 1.f; }
__device__ __forceinline__ float sigmoidf_(float x) { return 1.f / (1.f + __expf(-x)); }

#define MFMA_BF16(a, b, c) __builtin_amdgcn_mfma_f32_16x16x32_bf16((a), (b), (c), 0, 0, 0)

// ---------------------------------------------------------------------------
// K0: convert per-feature GRN weights f32 -> bf16, transposed [n][k].
// grid 128 = f*4+mat, block 512 (n = t&127, k-quarter = t>>7)
// ---------------------------------------------------------------------------
__global__ __launch_bounds__(512) void k0_prep(
    const float* __restrict__ fWe, const float* __restrict__ fWl,
    const float* __restrict__ fWgl, const float* __restrict__ fWgs,
    u16* __restrict__ wT)
{
  const int b = blockIdx.x, f = b >> 2, mat = b & 3;
  const float* srcs[4] = {fWe, fWl, fWgl, fWgs};
  const float* src = srcs[mat] + (size_t)f * 16384;   // [k=128][n=128]
  u16* dst = wT + (size_t)b * 16384;                  // [n=128][k=128]
  const int n = threadIdx.x & 127, qc = threadIdx.x >> 7;
  for (int k8 = qc * 4; k8 < qc * 4 + 4; ++k8) {
    u16x8 p;
#pragma unroll
    for (int j = 0; j < 8; ++j) p[j] = f2bf(src[(k8 * 8 + j) * 128 + n]);
    *(u16x8*)&dst[n * 128 + k8 * 8] = p;
  }
}

// ---------------------------------------------------------------------------
// K1: fused split-K  he_pre = v[:, :262144] @ cWe,  res_pre = v @ cWp
// grid 256 k-blocks; block 1024 thr (16 waves): waves 0-7 -> E, 8-15 -> P.
// Depth-2 register prefetch (two reg sets -> counted vmcnt), raw s_barrier
// with lgkmcnt(0) only so prefetch loads survive the barrier. XOR swizzled
// unpadded 128B LDS rows.
// ---------------------------------------------------------------------------
__global__ __launch_bounds__(1024) void k1_bigmm(
    const float* __restrict__ inp, const float* __restrict__ cWe,
    const float* __restrict__ cWp, float* __restrict__ outE, float* __restrict__ outP)
{
  __shared__ __align__(16) u16 xA[2][128][64];   // v tile [m][k=64] bf16 (swizzled)
  __shared__ __align__(16) u16 wE[2][128][64];   // cWe tile transposed [n][k] (swizzled)
  __shared__ __align__(16) u16 wP[2][128][64];   // cWp tile transposed [n][k] (swizzled)
  const int t = threadIdx.x;
  const int lane = t & 63, wv = t >> 6, quad = lane >> 4, l16 = lane & 15;
  const int mat = wv >> 3, wvm = wv & 7;         // compute role
  const int arow = t >> 3, af = t & 7;
  const int aslot = (af ^ (arow & 7)) * 8;
  const int wt = t & 511, wmi = t >> 9;          // staging role: matrix wmi
  const int wn = wt & 127, wkg = wt >> 7;        // n (lane-fast), k-group of 16
  const int wphi = (wn ^ (wn >> 2)) & 7;
  const float* Wm = wmi ? cWp : cWe;

  f32x4 acc[8];
#pragma unroll
  for (int n = 0; n < 8; ++n)
#pragma unroll
    for (int r = 0; r < 4; ++r) acc[n][r] = 0.f;

  const size_t kbase = (size_t)blockIdx.x * 1024;

  float4 av0[2], av1[2];
  float wv0[16], wv1[16];

  auto load_regs = [&](int it, float4* av, float* wr) {
    const size_t kk = kbase + (size_t)it * 64;
    av[0] = *(const float4*)(inp + (size_t)arow * 262144 + kk + af * 8);
    av[1] = *(const float4*)(inp + (size_t)arow * 262144 + kk + af * 8 + 4);
#pragma unroll
    for (int j = 0; j < 16; ++j)
      wr[j] = Wm[(kk + (size_t)(wkg * 16 + j)) * 128 + wn];
  };
  auto store_lds = [&](int buf, const float4* av, const float* wr) {
    u16x8 pa;
    pa[0] = f2bf(av[0].x); pa[1] = f2bf(av[0].y);
    pa[2] = f2bf(av[0].z); pa[3] = f2bf(av[0].w);
    pa[4] = f2bf(av[1].x); pa[5] = f2bf(av[1].y);
    pa[6] = f2bf(av[1].z); pa[7] = f2bf(av[1].w);
    *(u16x8*)&xA[buf][arow][aslot] = pa;
    u16 (*Wl)[64] = wmi ? wP[buf] : wE[buf];
#pragma unroll
    for (int s = 0; s < 2; ++s) {
      u16x8 pw;
#pragma unroll
      for (int j = 0; j < 8; ++j) pw[j] = f2bf(wr[s * 8 + j]);
      *(u16x8*)&Wl[wn][((wkg * 2 + s) ^ wphi) * 8] = pw;
    }
  };

  load_regs(0, av0, wv0);
  load_regs(1, av1, wv1);
  store_lds(0, av0, wv0);

  const int m = 16 * wvm + l16;
  const int phA = l16 & 7;
  const int phB = (l16 & 7) ^ (l16 >> 2);

  for (int it = 0; it < 16; ++it) {
    const int buf = it & 1;
    // counted barrier: drain LDS only; global prefetch stays in flight
    asm volatile("s_waitcnt lgkmcnt(0)" ::: "memory");
    __builtin_amdgcn_s_barrier();
    if (it < 14) {
      if (buf == 0) load_regs(it + 2, av0, wv0);
      else          load_regs(it + 2, av1, wv1);
    }
    const u16 (*Xb)[64] = xA[buf];
    const u16 (*WbT)[64] = mat ? wP[buf] : wE[buf];
#pragma unroll
    for (int ks = 0; ks < 2; ++ks) {
      const int slot = ks * 4 + quad;
      const bf16x8 a = *(const bf16x8*)&Xb[m][(slot ^ phA) * 8];
#pragma unroll
      for (int nt = 0; nt < 8; ++nt) {
        const bf16x8 b = *(const bf16x8*)&WbT[nt * 16 + l16][(slot ^ phB ^ ((nt & 1) * 4)) * 8];
        acc[nt] = MFMA_BF16(a, b, acc[nt]);
      }
    }
    if (it < 15) {
      if (buf == 0) store_lds(1, av1, wv1);   // data(it+1) lives in set (it+1)&1
      else          store_lds(0, av0, wv0);
    }
  }
  // C/D layout: col = lane&15, row = quad*4 + reg
  float* outp = mat ? outP : outE;
#pragma unroll
  for (int nt = 0; nt < 8; ++nt) {
    const int col = nt * 16 + l16;
#pragma unroll
    for (int r = 0; r < 4; ++r) {
      const int row = 16 * wvm + quad * 4 + r;
      atomicAdd(&outp[row * 128 + col], acc[nt][r]);
    }
  }
}

// ---------------------------------------------------------------------------
// K1b: static tail + concat-GRN chain + LN + softmax -> w[B,F]
// grid 128 (block = batch row), block 512: u = t&127, dc = t>>7 splits d-loops 4x
// ---------------------------------------------------------------------------
__global__ __launch_bounds__(512) void k1b_small(
    const float* __restrict__ stat,
    const float* __restrict__ cWe, const float* __restrict__ cbe,
    const float* __restrict__ cWl, const float* __restrict__ cbl,
    const float* __restrict__ cWgl, const float* __restrict__ cbgl,
    const float* __restrict__ cWgs, const float* __restrict__ cbgs,
    const float* __restrict__ cgam, const float* __restrict__ cbet,
    const float* __restrict__ cWp, const float* __restrict__ cbp,
    const float* __restrict__ Ws, const float* __restrict__ bs,
    const float* __restrict__ preE, const float* __restrict__ preP,
    float* __restrict__ wout)
{
  const int b = blockIdx.x, t = threadIdx.x;
  const int u = t & 127, dc = t >> 7;
  __shared__ float shS[128], shA[128], shB[128], par[8][132], red[4];
  if (t < 128) shS[t] = stat[b * 128 + t];
  __syncthreads();

  const float* we = cWe + (size_t)262144 * 128;
  const float* wp = cWp + (size_t)262144 * 128;
  float hp = 0.f, rp = 0.f;
  for (int d = dc * 32; d < dc * 32 + 32; ++d) {
    const float sv = shS[d];
    hp += sv * we[d * 128 + u];
    rp += sv * wp[d * 128 + u];
  }
  par[dc][u] = hp; par[4 + dc][u] = rp;
  __syncthreads();

  float rs = 0.f;
  if (t < 128) {
    const float he = preE[b * 128 + t] + cbe[t] + par[0][t] + par[1][t] + par[2][t] + par[3][t];
    rs = preP[b * 128 + t] + cbp[t] + par[4][t] + par[5][t] + par[6][t] + par[7][t];
    shA[t] = eluf(he);
  }
  __syncthreads();

  float p = 0.f;
  for (int d = dc * 32; d < dc * 32 + 32; ++d) p += shA[d] * cWl[d * 128 + u];
  par[dc][u] = p;
  __syncthreads();
  if (t < 128) shB[t] = cbl[t] + par[0][t] + par[1][t] + par[2][t] + par[3][t];
  __syncthreads();

  float gp = 0.f, sp = 0.f;
  for (int d = dc * 32; d < dc * 32 + 32; ++d) {
    const float hv = shB[d];
    gp += hv * cWgl[d * 128 + u];
    sp += hv * cWgs[d * 128 + u];
  }
  par[dc][u] = gp; par[4 + dc][u] = sp;
  __syncthreads();

  float z = 0.f;
  if (t < 128) {
    const float gl = cbgl[t] + par[0][t] + par[1][t] + par[2][t] + par[3][t];
    const float gs = cbgs[t] + par[4][t] + par[5][t] + par[6][t] + par[7][t];
    z = rs + gl * sigmoidf_(gs);
  }
  float s = z, q = z * z;
#pragma unroll
  for (int off = 32; off >= 1; off >>= 1) { s += __shfl_xor(s, off); q += __shfl_xor(q, off); }
  if ((t & 63) == 0 && t < 128) { red[(t >> 6) * 2] = s; red[(t >> 6) * 2 + 1] = q; }
  __syncthreads();
  if (t < 128) {
    const float S = red[0] + red[2], Q = red[1] + red[3];
    const float mean = S * (1.f / 128.f);
    const float var = Q * (1.f / 128.f) - mean * mean;
    const float rstd = rsqrtf(var + 1e-3f);
    shA[t] = (z - mean) * rstd * cgam[t] + cbet[t];
  }
  __syncthreads();
  if (t < 32) {
    float sj = bs[t];
    for (int uu = 0; uu < 128; ++uu) sj += shA[uu] * Ws[uu * 32 + t];
    float m = sj;
#pragma unroll
    for (int off = 16; off >= 1; off >>= 1) m = fmaxf(m, __shfl_xor(m, off));
    const float e = __expf(sj - m);
    float se = e;
#pragma unroll
    for (int off = 16; off >= 1; off >>= 1) se += __shfl_xor(se, off);
    wout[b * 32 + t] = e / se;
  }
}

// ---------------------------------------------------------------------------
// K2: per-feature GRN + LN + weighted combine. BARRIER-FREE.
// grid 1024 = bb(128, slow) x fg(8, fast -> one fg per XCD under round-robin);
// block 256 thr (4 waves); wave wv owns rows bb*64 + wv*16 .. +16 exclusively
// (xA/hA rows private per wave -> no __syncthreads anywhere).
// B-operands read directly from global wT (bf16 [n][k], L2-hot: 512KB/XCD).
// 4 features per block; racc over 4 fi; 8 atomics per output element total.
// ---------------------------------------------------------------------------
__global__ __launch_bounds__(256, 4) void k2_grn(
    const float* __restrict__ inp, const u16* __restrict__ wT,
    const float* __restrict__ fbe, const float* __restrict__ fbl,
    const float* __restrict__ fbgl, const float* __restrict__ fbgs,
    const float* __restrict__ fgam, const float* __restrict__ fbet,
    const float* __restrict__ wsel, float* __restrict__ out)
{
  __shared__ __align__(16) u16 xA[64][136];   // x tile bf16 (rows private/wave)
  __shared__ __align__(16) u16 hA[64][136];   // h then h2 (rows private/wave)
  const int t = threadIdx.x;
  const int lane = t & 63, wv = t >> 6, quad = lane >> 4, l16 = lane & 15;
  const int fg = blockIdx.x & 7, bb = blockIdx.x >> 3;
  const int rbase = wv * 16;                  // this wave's row block in xA/hA

  f32x4 acc[8], glr[8], racc[8];
#pragma unroll
  for (int n = 0; n < 8; ++n)
#pragma unroll
    for (int r = 0; r < 4; ++r) racc[n][r] = 0.f;

#define ZERO_ACC() do { _Pragma("unroll") \
  for (int n_ = 0; n_ < 8; ++n_) { acc[n_][0]=0.f; acc[n_][1]=0.f; acc[n_][2]=0.f; acc[n_][3]=0.f; } } while (0)

  // full-K GEMM: A rows from LDS (this wave's), B rows straight from global
  auto mm_g = [&](const u16 (*A)[136], const u16* __restrict__ wg, f32x4* ac) {
#pragma unroll
    for (int s = 0; s < 4; ++s) {
      const int kol = s * 32 + quad * 8;
      const bf16x8 a = *(const bf16x8*)&A[rbase + l16][kol];
#pragma unroll
      for (int nt = 0; nt < 8; ++nt) {
        const bf16x8 b = *(const bf16x8*)(wg + (size_t)(nt * 16 + l16) * 128 + kol);
        ac[nt] = MFMA_BF16(a, b, ac[nt]);
      }
    }
  };

  for (int fi = 0; fi < 4; ++fi) {
    const int f = fg * 4 + fi;
    const float wb = wsel[bb * 32 + f];
    const u16* wf = wT + (size_t)f * 65536;   // 4 mats x [128][128] bf16 [n][k]

    // ---- stage this wave's 16 rows of x (f32 -> bf16), per-wave private
    const float* xsrc = inp + (size_t)(bb * 64 + rbase) * 4096 + f * 128;
#pragma unroll
    for (int i = 0; i < 8; ++i) {
      const int idx = i * 64 + lane;          // 0..511 = 16 rows x 32 float4
      const int row = idx >> 5, fo = idx & 31;
      const float4 v = *(const float4*)(xsrc + (size_t)row * 4096 + fo * 4);
      u16x4 p; p[0] = f2bf(v.x); p[1] = f2bf(v.y); p[2] = f2bf(v.z); p[3] = f2bf(v.w);
      *(u16x4*)&xA[rbase + row][fo * 4] = p;
    }

    // ---- stage 1: h = elu(x @ We + be) -> hA (own rows)
    ZERO_ACC();
    mm_g(xA, wf, acc);
#pragma unroll
    for (int nt = 0; nt < 8; ++nt) {
      const int col = nt * 16 + l16;
      const float bv = fbe[f * 128 + col];
#pragma unroll
      for (int r = 0; r < 4; ++r)
        hA[rbase + quad * 4 + r][col] = f2bf(eluf(acc[nt][r] + bv));
    }

    // ---- stage 2: h2 = h @ Wl + bl -> hA (own rows, in place)
    ZERO_ACC();
    mm_g(hA, wf + 16384, acc);
#pragma unroll
    for (int nt = 0; nt < 8; ++nt) {
      const int col = nt * 16 + l16;
      const float bv = fbl[f * 128 + col];
#pragma unroll
      for (int r = 0; r < 4; ++r)
        hA[rbase + quad * 4 + r][col] = f2bf(acc[nt][r] + bv);
    }

    // ---- stage 3: gl = h2 @ Wgl + bgl (regs)
    ZERO_ACC();
    mm_g(hA, wf + 2 * 16384, acc);
#pragma unroll
    for (int nt = 0; nt < 8; ++nt) {
      const float bv = fbgl[f * 128 + nt * 16 + l16];
#pragma unroll
      for (int r = 0; r < 4; ++r) glr[nt][r] = acc[nt][r] + bv;
    }

    // ---- stage 4: gs = h2 @ Wgs + bgs
    ZERO_ACC();
    mm_g(hA, wf + 3 * 16384, acc);

    // ---- epilogue: g = gl*sigmoid(gs); z = x + g; LN per row; racc += wb*xg
#pragma unroll
    for (int nt = 0; nt < 8; ++nt) {
      const int col = nt * 16 + l16;
      const float bv = fbgs[f * 128 + col];
#pragma unroll
      for (int r = 0; r < 4; ++r) {
        const float g = glr[nt][r] * sigmoidf_(acc[nt][r] + bv);
        const float x = __uint_as_float(((unsigned int)xA[rbase + quad * 4 + r][col]) << 16);
        acc[nt][r] = x + g;  // z
      }
    }
    float sm[4], sq[4];
#pragma unroll
    for (int r = 0; r < 4; ++r) {
      float s = 0.f, q = 0.f;
#pragma unroll
      for (int nt = 0; nt < 8; ++nt) { const float zz = acc[nt][r]; s += zz; q += zz * zz; }
      sm[r] = s; sq[r] = q;
    }
#pragma unroll
    for (int off = 1; off <= 8; off <<= 1)
#pragma unroll
      for (int r = 0; r < 4; ++r) { sm[r] += __shfl_xor(sm[r], off); sq[r] += __shfl_xor(sq[r], off); }
#pragma unroll
    for (int r = 0; r < 4; ++r) {
      const float mean = sm[r] * (1.f / 128.f);
      const float var = sq[r] * (1.f / 128.f) - mean * mean;
      const float rstd = rsqrtf(var + 1e-3f);
      sm[r] = mean; sq[r] = rstd;
    }
#pragma unroll
    for (int nt = 0; nt < 8; ++nt) {
      const int col = nt * 16 + l16;
      const float gam = fgam[f * 128 + col];
      const float bet = fbet[f * 128 + col];
#pragma unroll
      for (int r = 0; r < 4; ++r) {
        const float xg = (acc[nt][r] - sm[r]) * sq[r] * gam + bet;
        racc[nt][r] += wb * xg;
      }
    }
  }

  // ---- one atomic per element per block (8 fg-blocks sum per element)
#pragma unroll
  for (int nt = 0; nt < 8; ++nt) {
    const int col = nt * 16 + l16;
#pragma unroll
    for (int r = 0; r < 4; ++r) {
      const int grow = bb * 64 + rbase + quad * 4 + r;
      atomicAdd(&out[(size_t)grow * 128 + col], racc[nt][r]);
    }
  }
#undef ZERO_ACC
}

extern "C" void kernel_launch(void* const* d_in, const int* in_sizes, int n_in,
                              void* d_out, int out_size, void* d_ws, size_t ws_size,
                              hipStream_t stream)
{
  const float* inp    = (const float*)d_in[0];
  const float* stat   = (const float*)d_in[1];
  const float* cWe    = (const float*)d_in[2];
  const float* cbe    = (const float*)d_in[3];
  const float* cWl    = (const float*)d_in[4];
  const float* cbl    = (const float*)d_in[5];
  const float* cWgl   = (const float*)d_in[6];
  const float* cbgl   = (const float*)d_in[7];
  const float* cWgs   = (const float*)d_in[8];
  const float* cbgs   = (const float*)d_in[9];
  const float* cgamma = (const float*)d_in[10];
  const float* cbeta  = (const float*)d_in[11];
  const float* cWp    = (const float*)d_in[12];
  const float* cbp    = (const float*)d_in[13];
  const float* Ws     = (const float*)d_in[14];
  const float* bs     = (const float*)d_in[15];
  const float* fWe    = (const float*)d_in[16];
  const float* fbe    = (const float*)d_in[17];
  const float* fWl    = (const float*)d_in[18];
  const float* fbl    = (const float*)d_in[19];
  const float* fWgl   = (const float*)d_in[20];
  const float* fbgl   = (const float*)d_in[21];
  const float* fWgs   = (const float*)d_in[22];
  const float* fbgs   = (const float*)d_in[23];
  const float* fgam   = (const float*)d_in[24];
  const float* fbet   = (const float*)d_in[25];

  float* ws_he  = (float*)d_ws;          // [128][128] he_pre accumulator
  float* ws_res = ws_he + 16384;         // [128][128] res_pre accumulator
  float* ws_w   = ws_res + 16384;        // [128][32]  softmax weights
  u16*   ws_wT  = (u16*)(ws_w + 4096);   // [32][4][128][128] bf16 transposed weights (4 MB)

  hipMemsetAsync(d_ws, 0, 32768 * sizeof(float), stream);              // he+res accumulators
  hipMemsetAsync(d_out, 0, (size_t)out_size * sizeof(float), stream);  // output accumulator
  k0_prep<<<128, 512, 0, stream>>>(fWe, fWl, fWgl, fWgs, ws_wT);
  k1_bigmm<<<256, 1024, 0, stream>>>(inp, cWe, cWp, ws_he, ws_res);
  k1b_small<<<128, 512, 0, stream>>>(stat, cWe, cbe, cWl, cbl, cWgl, cbgl, cWgs, cbgs,
                                     cgamma, cbeta, cWp, cbp, Ws, bs, ws_he, ws_res, ws_w);
  k2_grn<<<1024, 256, 0, stream>>>(inp, ws_wT, fbe, fbl, fbgl, fbgs,
                                   fgam, fbet, ws_w, (float*)d_out);
}

// Round 3
// 599.663 us; speedup vs baseline: 1.2764x; 1.2764x over previous
//
#include <hip/hip_runtime.h>

// VariableSelection (TFT-style) on gfx950. ALL I/O f32; bf16 MFMA internally.
// B=128 S=64 F=32 D=128 U=128 DS=128 DIN=262272, KMAIN=S*F*D=262144
// R6: k2 back to staged-WT dbuf pipeline at 3 blocks/CU: xA removed (GEMM1 A
//     direct from global, residual re-read from L2), hA/WT unpadded+XOR-swz,
//     fg-slow grid (atomic-safe), native bf16 cvt, setprio on MFMA.
//     k1 split E/P: 512 blocks x 512thr, 64KB LDS -> 2 blocks/CU overlap.

typedef unsigned short u16;
typedef __attribute__((ext_vector_type(4))) u16 u16x4;
typedef __attribute__((ext_vector_type(8))) u16 u16x8;
typedef __attribute__((ext_vector_type(8))) __bf16 bf16x8;
typedef __attribute__((ext_vector_type(4))) float f32x4;

__device__ __forceinline__ u16 f2bf(float f) {
  union { __bf16 b; u16 u; } c; c.b = (__bf16)f; return c.u;  // HW cvt, RNE
}
__device__ __forceinline__ float eluf(float x) { return x > 0.f ? x : __expf(x) - 1.f; }
__device__ __forceinline__ float sigmoidf_(float x) { return 1.f / (1.f + __expf(-x)); }

#define MFMA_BF16(a, b, c) __builtin_amdgcn_mfma_f32_16x16x32_bf16((a), (b), (c), 0, 0, 0)

// ---------------------------------------------------------------------------
// K0: convert per-feature GRN weights f32 -> bf16, transposed [n][k].
// grid 128 = f*4+mat, block 512 (n = t&127, k-quarter = t>>7)
// ---------------------------------------------------------------------------
__global__ __launch_bounds__(512) void k0_prep(
    const float* __restrict__ fWe, const float* __restrict__ fWl,
    const float* __restrict__ fWgl, const float* __restrict__ fWgs,
    u16* __restrict__ wT)
{
  const int b = blockIdx.x, f = b >> 2, mat = b & 3;
  const float* srcs[4] = {fWe, fWl, fWgl, fWgs};
  const float* src = srcs[mat] + (size_t)f * 16384;   // [k=128][n=128]
  u16* dst = wT + (size_t)b * 16384;                  // [n=128][k=128]
  const int n = threadIdx.x & 127, qc = threadIdx.x >> 7;
  for (int k8 = qc * 4; k8 < qc * 4 + 4; ++k8) {
    u16x8 p;
#pragma unroll
    for (int j = 0; j < 8; ++j) p[j] = f2bf(src[(k8 * 8 + j) * 128 + n]);
    *(u16x8*)&dst[n * 128 + k8 * 8] = p;
  }
}

// ---------------------------------------------------------------------------
// K1: split-K  he_pre = v @ cWe  (mat=0)  /  res_pre = v @ cWp  (mat=1)
// grid 512 = mat(2, slow) x kb(256); block 512 thr (8 waves, M=128 rows).
// mat-slow: the E/P pair sharing an inp tile lands on the same XCD -> L2 dedup.
// LDS 64KB -> 2 blocks/CU (cross-block overlap hides barriers/latency).
// XOR-swizzled unpadded 128B LDS rows; lgkm-only barrier.
// ---------------------------------------------------------------------------
__global__ __launch_bounds__(512) void k1_bigmm(
    const float* __restrict__ inp, const float* __restrict__ cWe,
    const float* __restrict__ cWp, float* __restrict__ outE, float* __restrict__ outP)
{
  __shared__ __align__(16) u16 xA[2][128][64];   // v tile [m][k=64] bf16 (swz)
  __shared__ __align__(16) u16 wB[2][128][64];   // W tile transposed [n][k] (swz)
  const int t = threadIdx.x;
  const int lane = t & 63, wv = t >> 6, quad = lane >> 4, l16 = lane & 15;
  const int mat = blockIdx.x >> 8, kb = blockIdx.x & 255;
  // A staging: thread = (row, 16-float group): 4 contiguous float4
  const int arow = t >> 2, ag = t & 3;
  // W staging: n-fast lanes (coalesced scalar loads)
  const int wn = t & 127, wkg = t >> 7;
  const int wphi = (wn ^ (wn >> 2)) & 7;
  const float* Wm = mat ? cWp : cWe;

  f32x4 acc[8];
#pragma unroll
  for (int n = 0; n < 8; ++n)
#pragma unroll
    for (int r = 0; r < 4; ++r) acc[n][r] = 0.f;

  const size_t kbase = (size_t)kb * 1024;
  float4 av[4]; float wr[16];

  auto load_regs = [&](int it) {
    const size_t kk = kbase + (size_t)it * 64;
    const float* ap = inp + (size_t)arow * 262144 + kk + ag * 16;
#pragma unroll
    for (int i = 0; i < 4; ++i) av[i] = *(const float4*)(ap + i * 4);
#pragma unroll
    for (int j = 0; j < 16; ++j)
      wr[j] = Wm[(kk + (size_t)(wkg * 16 + j)) * 128 + wn];
  };
  auto store_lds = [&](int buf) {
    const float* af = (const float*)av;
#pragma unroll
    for (int s = 0; s < 2; ++s) {
      u16x8 p;
#pragma unroll
      for (int j = 0; j < 8; ++j) p[j] = f2bf(af[s * 8 + j]);
      *(u16x8*)&xA[buf][arow][((ag * 2 + s) ^ (arow & 7)) * 8] = p;
    }
#pragma unroll
    for (int s = 0; s < 2; ++s) {
      u16x8 p;
#pragma unroll
      for (int j = 0; j < 8; ++j) p[j] = f2bf(wr[s * 8 + j]);
      *(u16x8*)&wB[buf][wn][((wkg * 2 + s) ^ wphi) * 8] = p;
    }
  };

  load_regs(0);
  store_lds(0);

  const int m = 16 * wv + l16;
  const int phA = l16 & 7;
  const int phB = (l16 & 7) ^ (l16 >> 2);

  for (int it = 0; it < 16; ++it) {
    const int buf = it & 1;
    asm volatile("s_waitcnt lgkmcnt(0)" ::: "memory");
    __builtin_amdgcn_s_barrier();
    if (it < 15) load_regs(it + 1);       // loads in flight during MFMA
    __builtin_amdgcn_s_setprio(1);
#pragma unroll
    for (int ks = 0; ks < 2; ++ks) {
      const int slot = ks * 4 + quad;
      const bf16x8 a = *(const bf16x8*)&xA[buf][m][(slot ^ phA) * 8];
#pragma unroll
      for (int nt = 0; nt < 8; ++nt) {
        const bf16x8 b = *(const bf16x8*)&wB[buf][nt * 16 + l16][(slot ^ phB ^ ((nt & 1) * 4)) * 8];
        acc[nt] = MFMA_BF16(a, b, acc[nt]);
      }
    }
    __builtin_amdgcn_s_setprio(0);
    if (it < 15) store_lds(buf ^ 1);      // vmcnt wait lands after MFMA block
  }
  // C/D layout: col = lane&15, row = quad*4 + reg
  float* outp = mat ? outP : outE;
#pragma unroll
  for (int nt = 0; nt < 8; ++nt) {
    const int col = nt * 16 + l16;
#pragma unroll
    for (int r = 0; r < 4; ++r) {
      const int row = 16 * wv + quad * 4 + r;
      atomicAdd(&outp[row * 128 + col], acc[nt][r]);
    }
  }
}

// ---------------------------------------------------------------------------
// K1b: static tail + concat-GRN chain + LN + softmax -> w[B,F]
// grid 128 (block = batch row), block 512: u = t&127, dc = t>>7 splits d-loops 4x
// ---------------------------------------------------------------------------
__global__ __launch_bounds__(512) void k1b_small(
    const float* __restrict__ stat,
    const float* __restrict__ cWe, const float* __restrict__ cbe,
    const float* __restrict__ cWl, const float* __restrict__ cbl,
    const float* __restrict__ cWgl, const float* __restrict__ cbgl,
    const float* __restrict__ cWgs, const float* __restrict__ cbgs,
    const float* __restrict__ cgam, const float* __restrict__ cbet,
    const float* __restrict__ cWp, const float* __restrict__ cbp,
    const float* __restrict__ Ws, const float* __restrict__ bs,
    const float* __restrict__ preE, const float* __restrict__ preP,
    float* __restrict__ wout)
{
  const int b = blockIdx.x, t = threadIdx.x;
  const int u = t & 127, dc = t >> 7;
  __shared__ float shS[128], shA[128], shB[128], par[8][132], red[4];
  if (t < 128) shS[t] = stat[b * 128 + t];
  __syncthreads();

  const float* we = cWe + (size_t)262144 * 128;
  const float* wp = cWp + (size_t)262144 * 128;
  float hp = 0.f, rp = 0.f;
  for (int d = dc * 32; d < dc * 32 + 32; ++d) {
    const float sv = shS[d];
    hp += sv * we[d * 128 + u];
    rp += sv * wp[d * 128 + u];
  }
  par[dc][u] = hp; par[4 + dc][u] = rp;
  __syncthreads();

  float rs = 0.f;
  if (t < 128) {
    const float he = preE[b * 128 + t] + cbe[t] + par[0][t] + par[1][t] + par[2][t] + par[3][t];
    rs = preP[b * 128 + t] + cbp[t] + par[4][t] + par[5][t] + par[6][t] + par[7][t];
    shA[t] = eluf(he);
  }
  __syncthreads();

  float p = 0.f;
  for (int d = dc * 32; d < dc * 32 + 32; ++d) p += shA[d] * cWl[d * 128 + u];
  par[dc][u] = p;
  __syncthreads();
  if (t < 128) shB[t] = cbl[t] + par[0][t] + par[1][t] + par[2][t] + par[3][t];
  __syncthreads();

  float gp = 0.f, sp = 0.f;
  for (int d = dc * 32; d < dc * 32 + 32; ++d) {
    const float hv = shB[d];
    gp += hv * cWgl[d * 128 + u];
    sp += hv * cWgs[d * 128 + u];
  }
  par[dc][u] = gp; par[4 + dc][u] = sp;
  __syncthreads();

  float z = 0.f;
  if (t < 128) {
    const float gl = cbgl[t] + par[0][t] + par[1][t] + par[2][t] + par[3][t];
    const float gs = cbgs[t] + par[4][t] + par[5][t] + par[6][t] + par[7][t];
    z = rs + gl * sigmoidf_(gs);
  }
  float s = z, q = z * z;
#pragma unroll
  for (int off = 32; off >= 1; off >>= 1) { s += __shfl_xor(s, off); q += __shfl_xor(q, off); }
  if ((t & 63) == 0 && t < 128) { red[(t >> 6) * 2] = s; red[(t >> 6) * 2 + 1] = q; }
  __syncthreads();
  if (t < 128) {
    const float S = red[0] + red[2], Q = red[1] + red[3];
    const float mean = S * (1.f / 128.f);
    const float var = Q * (1.f / 128.f) - mean * mean;
    const float rstd = rsqrtf(var + 1e-3f);
    shA[t] = (z - mean) * rstd * cgam[t] + cbet[t];
  }
  __syncthreads();
  if (t < 32) {
    float sj = bs[t];
    for (int uu = 0; uu < 128; ++uu) sj += shA[uu] * Ws[uu * 32 + t];
    float m = sj;
#pragma unroll
    for (int off = 16; off >= 1; off >>= 1) m = fmaxf(m, __shfl_xor(m, off));
    const float e = __expf(sj - m);
    float se = e;
#pragma unroll
    for (int off = 16; off >= 1; off >>= 1) se += __shfl_xor(se, off);
    wout[b * 32 + t] = e / se;
  }
}

// ---------------------------------------------------------------------------
// K2: per-feature GRN + LN + weighted combine over an 8-feature group.
// grid 512 = fg(4, slow) x bb(128, fast); block 256 thr (4 waves, M=64).
// WT[2] double-buffered (prefetch under MFMA, 8 barriers/fi); no xA: GEMM1 A
// converts straight from global f32 (compulsory HBM stream), residual x
// re-read from L2 in epilogue. hA/WT unpadded + XOR-swizzled (conflict-free).
// LDS 48KB -> 3 blocks/CU.
// ---------------------------------------------------------------------------
__global__ __launch_bounds__(256, 3) void k2_grn(
    const float* __restrict__ inp, const u16* __restrict__ wT,
    const float* __restrict__ fbe, const float* __restrict__ fbl,
    const float* __restrict__ fbgl, const float* __restrict__ fbgs,
    const float* __restrict__ fgam, const float* __restrict__ fbet,
    const float* __restrict__ wsel, float* __restrict__ out)
{
  __shared__ __align__(16) u16 hA[64][128];     // h then h2, rows private/wave (swz)
  __shared__ __align__(16) u16 WT[2][128][64];  // dbuf weight k-half [n][k] (swz)
  const int t = threadIdx.x;
  const int lane = t & 63, wv = t >> 6, quad = lane >> 4, l16 = lane & 15;
  const int fg = blockIdx.x >> 7, bb = blockIdx.x & 127;
  const int rbase = wv * 16;
  const int phB = (l16 & 7) ^ (l16 >> 2);
  const int arow = rbase + l16;                       // A-frag row (local)
  const int phH = (arow ^ (arow >> 2)) & 7;           // hA read swizzle

  f32x4 acc[8], glr[8], racc[8];
#pragma unroll
  for (int n = 0; n < 8; ++n)
#pragma unroll
    for (int r = 0; r < 4; ++r) racc[n][r] = 0.f;

#define ZERO_ACC() do { _Pragma("unroll") \
  for (int n_ = 0; n_ < 8; ++n_) { acc[n_][0]=0.f; acc[n_][1]=0.f; acc[n_][2]=0.f; acc[n_][3]=0.f; } } while (0)

  u16x8 wreg[4];
  auto wt_load = [&](const u16* src) {    // src = mat base + kh
#pragma unroll
    for (int i = 0; i < 4; ++i) {
      const int u = t + i * 256;
      wreg[i] = *(const u16x8*)(src + (size_t)(u >> 3) * 128 + (u & 7) * 8);
    }
  };
  auto wt_write = [&](int nb) {
#pragma unroll
    for (int i = 0; i < 4; ++i) {
      const int u = t + i * 256;
      const int n = u >> 3, j = u & 7;
      *(u16x8*)&WT[nb][n][(j ^ ((n ^ (n >> 2)) & 7)) * 8] = wreg[i];
    }
  };
  auto mmW = [&](int buf, int ks, bf16x8 a) {
#pragma unroll
    for (int nt = 0; nt < 8; ++nt) {
      const int sl = (ks * 4 + quad) ^ phB ^ ((nt & 1) * 4);
      const bf16x8 b = *(const bf16x8*)&WT[buf][nt * 16 + l16][sl * 8];
      acc[nt] = MFMA_BF16(a, b, acc[nt]);
    }
  };
  auto afrag_h = [&](int kh, int ks) -> bf16x8 {
    const int j = (kh >> 3) + ks * 4 + quad;
    return *(const bf16x8*)&hA[arow][((j ^ phH) & 15) * 8];
  };

  const float* xrow = inp + (size_t)(bb * 64 + arow) * 4096;     // + f*128
  const float* xre0 = inp + (size_t)(bb * 64 + rbase + quad * 4) * 4096 + l16;

  auto afrag_g = [&](const float* xb, int koff) -> bf16x8 {
    const float* p = xb + koff + quad * 8;
    const float4 a0 = *(const float4*)p;
    const float4 a1 = *(const float4*)(p + 4);
    union { u16x8 q; bf16x8 a; } c;
    c.q[0] = f2bf(a0.x); c.q[1] = f2bf(a0.y); c.q[2] = f2bf(a0.z); c.q[3] = f2bf(a0.w);
    c.q[4] = f2bf(a1.x); c.q[5] = f2bf(a1.y); c.q[6] = f2bf(a1.z); c.q[7] = f2bf(a1.w);
    return c.a;
  };
  auto store_h = [&](const float* bias, bool do_elu) {
#pragma unroll
    for (int nt = 0; nt < 8; ++nt) {
      const int col = nt * 16 + l16;
      const float bv = bias[col];
#pragma unroll
      for (int r = 0; r < 4; ++r) {
        const int row = rbase + quad * 4 + r;
        const float v = acc[nt][r] + bv;
        const int g = col >> 3;
        const int gg = (g ^ ((row ^ (row >> 2)) & 7)) & 15;
        hA[row][gg * 8 + (col & 7)] = f2bf(do_elu ? eluf(v) : v);
      }
    }
  };

  // prologue: We h0 of fi=0 -> WT[0]
  wt_load(wT + (size_t)(fg * 8) * 65536);
  wt_write(0);
  __syncthreads();

  for (int fi = 0; fi < 8; ++fi) {
    const int f = fg * 8 + fi;
    const float wb = wsel[bb * 32 + f];
    const u16* wfc = wT + (size_t)f * 65536;   // 4 mats x [128][128]
    const float* xb = xrow + f * 128;

    // u0: GEMM1 h0 (A global, WT[0]); prefetch We h1
    wt_load(wfc + 64);
    ZERO_ACC();
    __builtin_amdgcn_s_setprio(1);
#pragma unroll
    for (int ks = 0; ks < 2; ++ks) mmW(0, ks, afrag_g(xb, ks * 32));
    __builtin_amdgcn_s_setprio(0);
    wt_write(1); __syncthreads();

    // u1: GEMM1 h1 (WT[1]); prefetch Wl h0; h = elu(. + be) -> hA
    wt_load(wfc + 16384);
    __builtin_amdgcn_s_setprio(1);
#pragma unroll
    for (int ks = 0; ks < 2; ++ks) mmW(1, ks, afrag_g(xb, 64 + ks * 32));
    __builtin_amdgcn_s_setprio(0);
    store_h(fbe + f * 128, true);
    wt_write(0); __syncthreads();

    // u2: GEMM2 h0 (A hA, WT[0]); prefetch Wl h1
    wt_load(wfc + 16384 + 64);
    ZERO_ACC();
    __builtin_amdgcn_s_setprio(1);
#pragma unroll
    for (int ks = 0; ks < 2; ++ks) mmW(0, ks, afrag_h(0, ks));
    __builtin_amdgcn_s_setprio(0);
    wt_write(1); __syncthreads();

    // u3: GEMM2 h1 (WT[1]); prefetch Wgl h0; h2 -> hA (in place, own rows)
    wt_load(wfc + 2 * 16384);
    __builtin_amdgcn_s_setprio(1);
#pragma unroll
    for (int ks = 0; ks < 2; ++ks) mmW(1, ks, afrag_h(64, ks));
    __builtin_amdgcn_s_setprio(0);
    store_h(fbl + f * 128, false);
    wt_write(0); __syncthreads();

    // u4: GEMM3 h0 (WT[0]); prefetch Wgl h1
    wt_load(wfc + 2 * 16384 + 64);
    ZERO_ACC();
    __builtin_amdgcn_s_setprio(1);
#pragma unroll
    for (int ks = 0; ks < 2; ++ks) mmW(0, ks, afrag_h(0, ks));
    __builtin_amdgcn_s_setprio(0);
    wt_write(1); __syncthreads();

    // u5: GEMM3 h1 (WT[1]); prefetch Wgs h0; glr = acc + bgl
    wt_load(wfc + 3 * 16384);
    __builtin_amdgcn_s_setprio(1);
#pragma unroll
    for (int ks = 0; ks < 2; ++ks) mmW(1, ks, afrag_h(64, ks));
    __builtin_amdgcn_s_setprio(0);
#pragma unroll
    for (int nt = 0; nt < 8; ++nt) {
      const float bv = fbgl[f * 128 + nt * 16 + l16];
#pragma unroll
      for (int r = 0; r < 4; ++r) glr[nt][r] = acc[nt][r] + bv;
    }
    wt_write(0); __syncthreads();

    // u6: GEMM4 h0 (WT[0]); prefetch Wgs h1
    wt_load(wfc + 3 * 16384 + 64);
    ZERO_ACC();
    __builtin_amdgcn_s_setprio(1);
#pragma unroll
    for (int ks = 0; ks < 2; ++ks) mmW(0, ks, afrag_h(0, ks));
    __builtin_amdgcn_s_setprio(0);
    wt_write(1); __syncthreads();

    // u7: GEMM4 h1 (WT[1]); prefetch next fi's We h0; epilogue
    if (fi < 7) wt_load(wfc + 65536);
    __builtin_amdgcn_s_setprio(1);
#pragma unroll
    for (int ks = 0; ks < 2; ++ks) mmW(1, ks, afrag_h(64, ks));
    __builtin_amdgcn_s_setprio(0);

    // epilogue: g = gl*sigmoid(gs); z = x + g; LN per row; racc += wb*xg
    const float* xre = xre0 + f * 128;
#pragma unroll
    for (int nt = 0; nt < 8; ++nt) {
      const int col = nt * 16 + l16;
      const float bv = fbgs[f * 128 + col];
#pragma unroll
      for (int r = 0; r < 4; ++r) {
        const float g = glr[nt][r] * sigmoidf_(acc[nt][r] + bv);
        const float x = xre[(size_t)r * 4096 + nt * 16];
        acc[nt][r] = x + g;  // z
      }
    }
    float sm[4], sq[4];
#pragma unroll
    for (int r = 0; r < 4; ++r) {
      float s = 0.f, q = 0.f;
#pragma unroll
      for (int nt = 0; nt < 8; ++nt) { const float zz = acc[nt][r]; s += zz; q += zz * zz; }
      sm[r] = s; sq[r] = q;
    }
#pragma unroll
    for (int off = 1; off <= 8; off <<= 1)
#pragma unroll
      for (int r = 0; r < 4; ++r) { sm[r] += __shfl_xor(sm[r], off); sq[r] += __shfl_xor(sq[r], off); }
#pragma unroll
    for (int r = 0; r < 4; ++r) {
      const float mean = sm[r] * (1.f / 128.f);
      const float var = sq[r] * (1.f / 128.f) - mean * mean;
      const float rstd = rsqrtf(var + 1e-3f);
      sm[r] = mean; sq[r] = rstd;
    }
#pragma unroll
    for (int nt = 0; nt < 8; ++nt) {
      const int col = nt * 16 + l16;
      const float gam = fgam[f * 128 + col];
      const float bet = fbet[f * 128 + col];
#pragma unroll
      for (int r = 0; r < 4; ++r) {
        const float xg = (acc[nt][r] - sm[r]) * sq[r] * gam + bet;
        racc[nt][r] += wb * xg;
      }
    }
    if (fi < 7) wt_write(0);
    __syncthreads();
  }

  // ---- one atomic per element per block (4 fg-blocks sum per element)
#pragma unroll
  for (int nt = 0; nt < 8; ++nt) {
    const int col = nt * 16 + l16;
#pragma unroll
    for (int r = 0; r < 4; ++r) {
      const int grow = bb * 64 + rbase + quad * 4 + r;
      atomicAdd(&out[(size_t)grow * 128 + col], racc[nt][r]);
    }
  }
#undef ZERO_ACC
}

extern "C" void kernel_launch(void* const* d_in, const int* in_sizes, int n_in,
                              void* d_out, int out_size, void* d_ws, size_t ws_size,
                              hipStream_t stream)
{
  const float* inp    = (const float*)d_in[0];
  const float* stat   = (const float*)d_in[1];
  const float* cWe    = (const float*)d_in[2];
  const float* cbe    = (const float*)d_in[3];
  const float* cWl    = (const float*)d_in[4];
  const float* cbl    = (const float*)d_in[5];
  const float* cWgl   = (const float*)d_in[6];
  const float* cbgl   = (const float*)d_in[7];
  const float* cWgs   = (const float*)d_in[8];
  const float* cbgs   = (const float*)d_in[9];
  const float* cgamma = (const float*)d_in[10];
  const float* cbeta  = (const float*)d_in[11];
  const float* cWp    = (const float*)d_in[12];
  const float* cbp    = (const float*)d_in[13];
  const float* Ws     = (const float*)d_in[14];
  const float* bs     = (const float*)d_in[15];
  const float* fWe    = (const float*)d_in[16];
  const float* fbe    = (const float*)d_in[17];
  const float* fWl    = (const float*)d_in[18];
  const float* fbl    = (const float*)d_in[19];
  const float* fWgl   = (const float*)d_in[20];
  const float* fbgl   = (const float*)d_in[21];
  const float* fWgs   = (const float*)d_in[22];
  const float* fbgs   = (const float*)d_in[23];
  const float* fgam   = (const float*)d_in[24];
  const float* fbet   = (const float*)d_in[25];

  float* ws_he  = (float*)d_ws;          // [128][128] he_pre accumulator
  float* ws_res = ws_he + 16384;         // [128][128] res_pre accumulator
  float* ws_w   = ws_res + 16384;        // [128][32]  softmax weights
  u16*   ws_wT  = (u16*)(ws_w + 4096);   // [32][4][128][128] bf16 transposed weights (4 MB)

  hipMemsetAsync(d_ws, 0, 32768 * sizeof(float), stream);              // he+res accumulators
  hipMemsetAsync(d_out, 0, (size_t)out_size * sizeof(float), stream);  // output accumulator
  k0_prep<<<128, 512, 0, stream>>>(fWe, fWl, fWgl, fWgs, ws_wT);
  k1_bigmm<<<512, 512, 0, stream>>>(inp, cWe, cWp, ws_he, ws_res);
  k1b_small<<<128, 512, 0, stream>>>(stat, cWe, cbe, cWl, cbl, cWgl, cbgl, cWgs, cbgs,
                                     cgamma, cbeta, cWp, cbp, Ws, bs, ws_he, ws_res, ws_w);
  k2_grn<<<512, 256, 0, stream>>>(inp, ws_wT, fbe, fbl, fbgl, fbgs,
                                  fgam, fbet, ws_w, (float*)d_out);
}